// Round 7
// baseline (323.700 us; speedup 1.0000x reference)
//
#include <hip/hip_runtime.h>

// ---------------------------------------------------------------------------
// Attention_33638183862624  (linear "Taylor-softmax" attention)
// B=16, C=512, CQK=64, N=4096.  fp32 in/out, bf16 MFMA internally.
// ATTRIBUTION (R5/R6 shadow rounds):
//   fixed harness floor ~220us; kernels sum ~100us: k_qk 27 (floor 24),
//   k_t 26, k_red 3, k_mat ~9, k_out 22 = write roofline (81% HBM peak).
// R7 = 321.2us (best).  R8: exploit R3's measured equivalence (atomicAdd
//   T-accumulation == partial stores) in reverse: drop Tpart+k_red entirely,
//   k_t atomicAdds into T (2MB, L2-hot, zeroed by k_prep).  5 dispatches.
//   gfx950 note: LDS dbuf pointer ARRAYS indexed by runtime values fail to
//   compile; use smem + pb*OFFSET arithmetic (k_out).
// ---------------------------------------------------------------------------

typedef __attribute__((ext_vector_type(8))) short short8_t;
typedef __attribute__((ext_vector_type(4))) float f32x4;

__device__ __forceinline__ unsigned short f2bf(float f) {
  union { float f; unsigned u; } v; v.f = f;
  unsigned r = v.u + 0x7FFFu + ((v.u >> 16) & 1u);   // RNE
  return (unsigned short)(r >> 16);
}
__device__ __forceinline__ float bf2f(unsigned short h) {
  union { unsigned u; float f; } v; v.u = ((unsigned)h) << 16;
  return v.f;
}

#define MFMA(a, b, c) __builtin_amdgcn_mfma_f32_16x16x32_bf16((a), (b), (c), 0, 0, 0)

// ---------------------------------------------------------------------------
// k_prep: pack Wq/Wk into bf16 [128][512]; zero xsum/Ksum/T.
// ---------------------------------------------------------------------------
__global__ void k_prep(const float* __restrict__ Wq, const float* __restrict__ Wk,
                       unsigned short* __restrict__ Wqk,
                       float* __restrict__ xsum, float* __restrict__ Ksum,
                       float* __restrict__ T) {
  int idx = blockIdx.x * 256 + threadIdx.x;       // 65536 total
  int o = idx >> 9, c = idx & 511;
  float v = (o < 64) ? Wq[o * 512 + c] : Wk[(o - 64) * 512 + c];
  Wqk[idx] = f2bf(v);
  if (idx < 8192) xsum[idx] = 0.f;
  if (idx < 1024) Ksum[idx] = 0.f;
  // zero T: 524288 floats = 131072 f32x4, 2 per thread
  f32x4 z = (f32x4){0.f, 0.f, 0.f, 0.f};
  ((f32x4*)T)[idx * 2] = z;
  ((f32x4*)T)[idx * 2 + 1] = z;
}

// ---------------------------------------------------------------------------
// k_qk: per batch GEMM QK[128 o][4096 n] = Wqk[128][512] * x[512][4096]
// (27us vs 24us traffic floor -- done.)
// ---------------------------------------------------------------------------
__launch_bounds__(256, 2)
__global__ void k_qk(const float* __restrict__ x, const unsigned short* __restrict__ Wqk,
                     const float* __restrict__ bq, const float* __restrict__ bk,
                     unsigned short* __restrict__ QnT, unsigned short* __restrict__ KnG,
                     float* __restrict__ Ksum) {
  __shared__ __align__(16) unsigned char smem[77312];
  unsigned short* SAb[2] = {(unsigned short*)(smem + 0),
                            (unsigned short*)(smem + 18432)};   // 128 x 72 each
  unsigned short* SBb[2] = {(unsigned short*)(smem + 36864),
                            (unsigned short*)(smem + 55296)};   // 128 x 72 each
  unsigned short* EQ = (unsigned short*)(smem + 0);       // 128 x 72 (epilogue)
  unsigned short* EK = (unsigned short*)(smem + 18432);   // 64 x 136 (epilogue)
  float* ssq   = (float*)(smem + 73728);                  // [4][128]
  float* invq  = (float*)(smem + 75776);                  // [128]
  float* invk  = (float*)(smem + 76288);                  // [128]
  float* biasL = (float*)(smem + 76800);                  // [128]

  const int t = threadIdx.x;
  const int lane = t & 63, w = t >> 6;
  const int l15 = lane & 15, quad = lane >> 4;
  const int nt = blockIdx.x, b = blockIdx.y;
  const int n0 = nt * 128;
  const float* xb = x + (size_t)b * 512 * 4096;

  if (t < 128) biasL[t] = (t < 64) ? bq[t] : bk[t - 64];

  f32x4 acc[2][8];
#pragma unroll
  for (int i = 0; i < 2; ++i)
#pragma unroll
    for (int j = 0; j < 8; ++j) acc[i][j] = (f32x4){0.f, 0.f, 0.f, 0.f};

  const int nB = t & 127;
  const int cgB = t >> 7;
  const float* bsrc0 = xb + (size_t)(cgB * 32) * 4096 + n0 + nB;

  short8_t apre[4];
  float bpre[32];

#define QK_LOADA(kc_) do {                                                     \
    const int c0_ = (kc_) * 64;                                                \
    _Pragma("unroll")                                                          \
    for (int p = 0; p < 4; ++p) {                                              \
      int gid = t + p * 256; int o_ = gid >> 3, cg = gid & 7;                  \
      apre[p] = *(const short8_t*)(Wqk + o_ * 512 + c0_ + cg * 8);             \
    } } while (0)

#define QK_LOADB(kc_) do {                                                     \
    const float* s_ = bsrc0 + (size_t)(kc_) * 64 * 4096;                       \
    _Pragma("unroll")                                                          \
    for (int i = 0; i < 32; ++i) bpre[i] = s_[(size_t)i * 4096];               \
    } while (0)

#define QK_STORE(pb) do {                                                      \
    unsigned short* SAp = SAb[pb]; unsigned short* SBp = SBb[pb];              \
    _Pragma("unroll")                                                          \
    for (int p = 0; p < 4; ++p) {                                              \
      int gid = t + p * 256; int o_ = gid >> 3, cg = gid & 7;                  \
      *(short8_t*)(SAp + o_ * 72 + cg * 8) = apre[p];                          \
    }                                                                          \
    _Pragma("unroll")                                                          \
    for (int j = 0; j < 4; ++j) {                                              \
      short8_t v_;                                                             \
      _Pragma("unroll")                                                        \
      for (int e = 0; e < 8; ++e) v_[e] = (short)f2bf(bpre[j * 8 + e]);        \
      *(short8_t*)(SBp + nB * 72 + cgB * 32 + j * 8) = v_;                     \
    } } while (0)

#define QK_MM(pb) do {                                                         \
    const unsigned short* SAp = SAb[pb]; const unsigned short* SBp = SBb[pb];  \
    _Pragma("unroll")                                                          \
    for (int s = 0; s < 2; ++s) {                                              \
      short8_t a0 = *(const short8_t*)(SAp + (w * 32 + l15) * 72 + s * 32 + quad * 8);      \
      short8_t a1 = *(const short8_t*)(SAp + (w * 32 + 16 + l15) * 72 + s * 32 + quad * 8); \
      _Pragma("unroll")                                                        \
      for (int tc = 0; tc < 8; ++tc) {                                         \
        short8_t bf_ = *(const short8_t*)(SBp + (tc * 16 + l15) * 72 + s * 32 + quad * 8);  \
        acc[0][tc] = MFMA(a0, bf_, acc[0][tc]);                                \
        acc[1][tc] = MFMA(a1, bf_, acc[1][tc]);                                \
      } } } while (0)

  QK_LOADA(0); QK_LOADB(0);
#pragma unroll
  for (int kc = 0; kc < 8; ++kc) {
    const int pb = kc & 1;
    QK_STORE(pb);
    if (kc < 7) { QK_LOADA(kc + 1); QK_LOADB(kc + 1); }
    __syncthreads();
    QK_MM(pb);
  }
  __syncthreads();

#pragma unroll
  for (int trl = 0; trl < 2; ++trl)
#pragma unroll
    for (int reg = 0; reg < 4; ++reg) {
      int o = w * 32 + trl * 16 + quad * 4 + reg;
      float bias = biasL[o];
#pragma unroll
      for (int tc = 0; tc < 8; ++tc) acc[trl][tc][reg] += bias;
    }

#pragma unroll
  for (int tc = 0; tc < 8; ++tc) {
    float v = 0.f;
#pragma unroll
    for (int trl = 0; trl < 2; ++trl)
#pragma unroll
      for (int reg = 0; reg < 4; ++reg) {
        float q = acc[trl][tc][reg];
        v += q * q;
      }
    v += __shfl_xor(v, 16);
    v += __shfl_xor(v, 32);
    if (quad == 0) ssq[w * 128 + tc * 16 + l15] = v;
  }
  __syncthreads();
  if (t < 128) {
    float qs = ssq[t] + ssq[128 + t];
    float ks = ssq[256 + t] + ssq[384 + t];
    invq[t] = 1.0f / fmaxf(sqrtf(qs), 1e-6f);
    invk[t] = 1.0f / fmaxf(sqrtf(ks), 1e-6f);
  }
  __syncthreads();

  if (w < 2) {
#pragma unroll
    for (int trl = 0; trl < 2; ++trl)
#pragma unroll
      for (int tc = 0; tc < 8; ++tc) {
        int n = tc * 16 + l15;
        float inv = invq[n];
#pragma unroll
        for (int reg = 0; reg < 4; ++reg) {
          int o = w * 32 + trl * 16 + quad * 4 + reg;
          EQ[n * 72 + o] = f2bf(acc[trl][tc][reg] * inv);
        }
      }
  } else {
#pragma unroll
    for (int trl = 0; trl < 2; ++trl)
#pragma unroll
      for (int reg = 0; reg < 4; ++reg) {
        int m = (w - 2) * 32 + trl * 16 + quad * 4 + reg;
        float p = 0.f;
#pragma unroll
        for (int tc = 0; tc < 8; ++tc) {
          int n = tc * 16 + l15;
          float val = acc[trl][tc][reg] * invk[n];
          EK[m * 136 + n] = f2bf(val);
          p += val;
        }
        p += __shfl_xor(p, 1);
        p += __shfl_xor(p, 2);
        p += __shfl_xor(p, 4);
        p += __shfl_xor(p, 8);
        if (l15 == 0) atomicAdd(Ksum + b * 64 + m, p);
      }
  }
  __syncthreads();

  unsigned short* qdst = QnT + ((size_t)b * 4096 + n0) * 64;
#pragma unroll
  for (int p = 0; p < 4; ++p) {
    int idx = t + p * 256;
    int row = idx >> 3, seg = idx & 7;
    *(short8_t*)(qdst + row * 64 + seg * 8) = *(const short8_t*)(EQ + row * 72 + seg * 8);
  }
  unsigned short* kdst = KnG + (size_t)b * 64 * 4096 + n0;
#pragma unroll
  for (int p = 0; p < 4; ++p) {
    int idx = t + p * 256;
    int row = idx >> 4, seg = idx & 15;
    *(short8_t*)(kdst + (size_t)row * 4096 + seg * 8) =
        *(const short8_t*)(EK + row * 136 + seg * 8);
  }
#undef QK_LOADA
#undef QK_LOADB
#undef QK_STORE
#undef QK_MM
}

// ---------------------------------------------------------------------------
// k_t:  T[b][64 m][512 k] += sum_{n in split ns} Kn[m,n]*x[k,n]  (atomicAdd;
// R3 measured atomics == partial-stores, and this drops k_red + 35MB traffic)
// + xsum atomics + tailor[b][n] (Ksum final here).  BK=64 dbuf+prefetch.
// grid (8 nsplits, 4 ctiles, 16 batches), 256 threads.
// ---------------------------------------------------------------------------
__launch_bounds__(256, 2)
__global__ void k_t(const float* __restrict__ x, const unsigned short* __restrict__ KnG,
                    float* __restrict__ T, float* __restrict__ xsum,
                    const unsigned short* __restrict__ QnT,
                    const float* __restrict__ Ksum, float* __restrict__ tailor) {
  __shared__ __align__(16) unsigned char smem[55552];
  unsigned short* SAb[2] = {(unsigned short*)(smem + 0),
                            (unsigned short*)(smem + 9216)};    // 64 x 72 each
  unsigned short* SBb[2] = {(unsigned short*)(smem + 18432),
                            (unsigned short*)(smem + 36864)};   // 128 x 72 each
  float* Ksl = (float*)(smem + 55296);                          // [64]
  const int t = threadIdx.x;
  const int lane = t & 63, w = t >> 6;
  const int l15 = lane & 15, quad = lane >> 4;
  const int ns = blockIdx.x, ct = blockIdx.y, b = blockIdx.z;
  const int c0 = ct * 128;
  const float* xb = x + (size_t)b * 512 * 4096;
  const unsigned short* Knb = KnG + (size_t)b * 64 * 4096 + ns * 512;

  if (t < 64) Ksl[t] = Ksum[b * 64 + t];

  f32x4 acc[4][2];
#pragma unroll
  for (int i = 0; i < 4; ++i)
#pragma unroll
    for (int j = 0; j < 2; ++j) acc[i][j] = (f32x4){0.f, 0.f, 0.f, 0.f};

  const int row = t >> 1, half = t & 1;
  float xs = 0.f;
  const float* bbase = xb + (size_t)(c0 + row) * 4096 + ns * 512 + half * 32;

  short8_t apre[2];
  f32x4 bpre[8];

#define T_LOADA(ch_) do {                                                      \
    _Pragma("unroll")                                                          \
    for (int p = 0; p < 2; ++p) {                                              \
      int gid = t + p * 256; int m_ = gid >> 3, cg = gid & 7;                  \
      apre[p] = *(const short8_t*)(Knb + (size_t)m_ * 4096 + (ch_) * 64 + cg * 8); \
    } } while (0)

#define T_LOADB(ch_) do {                                                      \
    const float* s_ = bbase + (ch_) * 64;                                      \
    _Pragma("unroll")                                                          \
    for (int q = 0; q < 8; ++q) bpre[q] = *(const f32x4*)(s_ + q * 4);         \
    } while (0)

#define T_STORE(pb) do {                                                       \
    unsigned short* SAp = SAb[pb]; unsigned short* SBp = SBb[pb];              \
    _Pragma("unroll")                                                          \
    for (int p = 0; p < 2; ++p) {                                              \
      int gid = t + p * 256; int m_ = gid >> 3, cg = gid & 7;                  \
      *(short8_t*)(SAp + m_ * 72 + cg * 8) = apre[p];                          \
    }                                                                          \
    _Pragma("unroll")                                                          \
    for (int j = 0; j < 4; ++j) {                                              \
      short8_t v_;                                                             \
      _Pragma("unroll")                                                        \
      for (int e = 0; e < 4; ++e) {                                            \
        float f0 = bpre[j * 2][e], f1 = bpre[j * 2 + 1][e];                    \
        xs += f0 + f1;                                                         \
        v_[e] = (short)f2bf(f0); v_[4 + e] = (short)f2bf(f1);                  \
      }                                                                        \
      *(short8_t*)(SBp + row * 72 + half * 32 + j * 8) = v_;                   \
    } } while (0)

#define T_MM(pb) do {                                                          \
    const unsigned short* SAp = SAb[pb]; const unsigned short* SBp = SBb[pb];  \
    _Pragma("unroll")                                                          \
    for (int s = 0; s < 2; ++s) {                                              \
      short8_t af[4];                                                          \
      _Pragma("unroll")                                                        \
      for (int tm = 0; tm < 4; ++tm)                                           \
        af[tm] = *(const short8_t*)(SAp + (tm * 16 + l15) * 72 + s * 32 + quad * 8); \
      _Pragma("unroll")                                                        \
      for (int tcl = 0; tcl < 2; ++tcl) {                                      \
        short8_t bf_ = *(const short8_t*)(SBp + (w * 32 + tcl * 16 + l15) * 72 + s * 32 + quad * 8); \
        _Pragma("unroll")                                                      \
        for (int tm = 0; tm < 4; ++tm) acc[tm][tcl] = MFMA(af[tm], bf_, acc[tm][tcl]); \
      } } } while (0)

  T_LOADA(0); T_LOADB(0);
#pragma unroll
  for (int ch = 0; ch < 8; ++ch) {
    const int pb = ch & 1;
    T_STORE(pb);
    if (ch < 7) { T_LOADA(ch + 1); T_LOADB(ch + 1); }
    __syncthreads();
    if (ch == 0 && t < 128) {
      int n = ns * 512 + ct * 128 + t;
      const unsigned short* q = QnT + ((size_t)b * 4096 + n) * 64;
      float d = 0.f;
#pragma unroll
      for (int s8 = 0; s8 < 8; ++s8) {
        short8_t qv = *(const short8_t*)(q + s8 * 8);
#pragma unroll
        for (int e = 0; e < 8; ++e)
          d += bf2f((unsigned short)qv[e]) * Ksl[s8 * 8 + e];
      }
      tailor[b * 4096 + n] = 1.0f / fmaxf(4096.0f + d, 1e-6f);
    }
    T_MM(pb);
  }

  xs += __shfl_xor(xs, 1);
  if (half == 0) atomicAdd(xsum + b * 512 + c0 + row, xs);
  // T accumulation: direct atomics (8-way split-K contention, measured-null)
#pragma unroll
  for (int tm = 0; tm < 4; ++tm)
#pragma unroll
    for (int tcl = 0; tcl < 2; ++tcl)
#pragma unroll
      for (int reg = 0; reg < 4; ++reg) {
        int m = tm * 16 + quad * 4 + reg;
        int c = c0 + w * 32 + tcl * 16 + l15;
        atomicAdd(T + ((size_t)b * 64 + m) * 512 + c, acc[tm][tcl][reg]);
      }
#undef T_LOADA
#undef T_LOADB
#undef T_STORE
#undef T_MM
}

// ---------------------------------------------------------------------------
// k_mat: matrix[m][c] = sum_k T[m][k]*Wv[c][k] + bv[c]*Ksum[m] -> matT[c][m]
//        Vsum[c] = Wv[c,:]*xsum + 4096*bv[c]
// 2m x 4c register blocking, f32x4 LDS reads.  Reads reduced T (2MB, L2-hot).
// grid (16 cblocks, 16 batches), 256 threads; c-range 32 per block.
// ---------------------------------------------------------------------------
__launch_bounds__(256, 2)
__global__ void k_mat(const float* __restrict__ T, const float* __restrict__ Wv,
                      const float* __restrict__ bv, const float* __restrict__ xsum,
                      const float* __restrict__ Ksum,
                      unsigned short* __restrict__ matT, float* __restrict__ Vsum) {
  __shared__ __align__(16) unsigned char smem[27136];
  float* ST = (float*)smem;             // 64 x 68
  float* SW = (float*)(smem + 17408);   // 32 x 68
  float* SV = (float*)(smem + 26112);   // 256
  const int t = threadIdx.x;
  const int cb = blockIdx.x, b = blockIdx.y;
  const int c0 = cb * 32;
  const int mp = t >> 3, cs = t & 7;    // rows {2mp,2mp+1}, cols {cs+8j}
  f32x4 acc0 = (f32x4){0.f, 0.f, 0.f, 0.f};
  f32x4 acc1 = (f32x4){0.f, 0.f, 0.f, 0.f};

  for (int kc = 0; kc < 8; ++kc) {
    __syncthreads();
#pragma unroll
    for (int p = 0; p < 4; ++p) {
      int idx = t + p * 256;
      int row = idx >> 4, f4 = idx & 15;
      *(f32x4*)(ST + row * 68 + f4 * 4) =
          *(const f32x4*)(T + ((size_t)b * 64 + row) * 512 + kc * 64 + f4 * 4);
    }
#pragma unroll
    for (int p = 0; p < 2; ++p) {
      int idx = t + p * 256;
      int row = idx >> 4, f4 = idx & 15;
      *(f32x4*)(SW + row * 68 + f4 * 4) =
          *(const f32x4*)(Wv + (size_t)(c0 + row) * 512 + kc * 64 + f4 * 4);
    }
    __syncthreads();
#pragma unroll 4
    for (int kk = 0; kk < 64; kk += 4) {
      f32x4 t0 = *(const f32x4*)(ST + (2 * mp) * 68 + kk);
      f32x4 t1 = *(const f32x4*)(ST + (2 * mp + 1) * 68 + kk);
#pragma unroll
      for (int j = 0; j < 4; ++j) {
        f32x4 wv = *(const f32x4*)(SW + (cs + j * 8) * 68 + kk);
#pragma unroll
        for (int e = 0; e < 4; ++e) {
          acc0[j] = fmaf(t0[e], wv[e], acc0[j]);
          acc1[j] = fmaf(t1[e], wv[e], acc1[j]);
        }
      }
    }
  }
  float ks0 = Ksum[b * 64 + 2 * mp];
  float ks1 = Ksum[b * 64 + 2 * mp + 1];
#pragma unroll
  for (int j = 0; j < 4; ++j) {
    int c = c0 + cs + j * 8;
    float bvc = bv[c];
    unsigned lo = f2bf(acc0[j] + bvc * ks0);
    unsigned hi = f2bf(acc1[j] + bvc * ks1);
    *(unsigned*)(matT + ((size_t)b * 512 + c) * 64 + 2 * mp) = lo | (hi << 16);
  }
  {
    int cc = t >> 3, kp = t & 7;
    const float* wr = Wv + (size_t)(c0 + cc) * 512 + kp * 64;
    const float* xr = xsum + b * 512 + kp * 64;
    float s = 0.f;
    for (int i = 0; i < 64; ++i) s += wr[i] * xr[i];
    SV[cc * 8 + kp] = s;
  }
  __syncthreads();
  if (t < 32) {
    float s = 0.f;
#pragma unroll
    for (int i = 0; i < 8; ++i) s += SV[t * 8 + i];
    int c = c0 + t;
    Vsum[b * 512 + c] = s + 4096.0f * bv[c];
  }
}

// ---------------------------------------------------------------------------
// k_out: ct-merged (R6).  grid (32 nt, 16 b), 256 threads.  Stage QnT/tail/
// Vsum once; loop ct=0..3 with reg-prefetch + LDS dbuf (byte-offset
// arithmetic) for matT; MFMA + store per ct.  22us = write roofline.
// ---------------------------------------------------------------------------
__launch_bounds__(256, 2)
__global__ void k_out(const unsigned short* __restrict__ QnT,
                      const unsigned short* __restrict__ matT,
                      const float* __restrict__ tailG, const float* __restrict__ Vsum,
                      const float* __restrict__ gamma, float* __restrict__ out) {
  __shared__ __align__(16) unsigned char smem[57856];
  unsigned short* SB = (unsigned short*)(smem + 36864);   // 128 x 72 (QnT)
  float* tail = (float*)(smem + 55296);                   // 128
  float* vs   = (float*)(smem + 55808);                   // 512
  const int t = threadIdx.x;
  const int lane = t & 63, w = t >> 6;
  const int l15 = lane & 15, quad = lane >> 4;
  const int nt = blockIdx.x, b = blockIdx.y;
  const int n0 = nt * 128;

  const unsigned short* bsrc = QnT + ((size_t)b * 4096 + n0) * 64;
#pragma unroll
  for (int p = 0; p < 4; ++p) {
    int idx = t + p * 256;
    int row = idx >> 3, seg = idx & 7;
    *(short8_t*)(SB + row * 72 + seg * 8) = *(const short8_t*)(bsrc + row * 64 + seg * 8);
  }
  if (t < 128) tail[t] = tailG[b * 4096 + n0 + t];
  vs[t] = Vsum[b * 512 + t];
  vs[256 + t] = Vsum[b * 512 + 256 + t];
  const float g = gamma[0];
  float* ob = out + (size_t)b * 512 * 4096;
  const unsigned short* asrc = matT + (size_t)b * 512 * 64;

  short8_t areg[4];
#pragma unroll
  for (int p = 0; p < 4; ++p) {
    int idx = t + p * 256;
    int row = idx >> 3, seg = idx & 7;
    areg[p] = *(const short8_t*)(asrc + row * 64 + seg * 8);
  }
  for (int ct = 0; ct < 4; ++ct) {
    unsigned short* SAp = (unsigned short*)(smem + (ct & 1) * 18432);
#pragma unroll
    for (int p = 0; p < 4; ++p) {
      int idx = t + p * 256;
      int row = idx >> 3, seg = idx & 7;
      *(short8_t*)(SAp + row * 72 + seg * 8) = areg[p];
    }
    if (ct < 3) {
      const unsigned short* an = asrc + (size_t)(ct + 1) * 128 * 64;
#pragma unroll
      for (int p = 0; p < 4; ++p) {
        int idx = t + p * 256;
        int row = idx >> 3, seg = idx & 7;
        areg[p] = *(const short8_t*)(an + row * 64 + seg * 8);
      }
    }
    __syncthreads();
    f32x4 acc[2][8];
#pragma unroll
    for (int i = 0; i < 2; ++i)
#pragma unroll
      for (int j = 0; j < 8; ++j) acc[i][j] = (f32x4){0.f, 0.f, 0.f, 0.f};
#pragma unroll
    for (int s = 0; s < 2; ++s) {
      short8_t a0 = *(const short8_t*)(SAp + (w * 32 + l15) * 72 + s * 32 + quad * 8);
      short8_t a1 = *(const short8_t*)(SAp + (w * 32 + 16 + l15) * 72 + s * 32 + quad * 8);
#pragma unroll
      for (int tc = 0; tc < 8; ++tc) {
        short8_t bfr = *(const short8_t*)(SB + (tc * 16 + l15) * 72 + s * 32 + quad * 8);
        acc[0][tc] = MFMA(a0, bfr, acc[0][tc]);
        acc[1][tc] = MFMA(a1, bfr, acc[1][tc]);
      }
    }
    const int c0 = ct * 128;
#pragma unroll
    for (int trl = 0; trl < 2; ++trl)
#pragma unroll
      for (int tc = 0; tc < 8; ++tc) {
        int n = tc * 16 + l15;
        float tl = tail[n] * g;
#pragma unroll
        for (int reg = 0; reg < 4; ++reg) {
          int cl = w * 32 + trl * 16 + quad * 4 + reg;
          float val = tl * (vs[c0 + cl] + acc[trl][tc][reg]);
          ob[(size_t)(c0 + cl) * 4096 + n0 + n] = val;
        }
      }
    __syncthreads();
  }
}

// ---------------------------------------------------------------------------
// workspace layout (bytes):
//   T      @ 0        : 16*64*512*4  = 2,097,152   (zeroed by k_prep)
//   xsum   @ 2097152  : 32,768       (zeroed by k_prep)
//   Ksum   @ 2129920  : 4,096        (zeroed by k_prep)
//   Vsum   @ 2134016  : 32,768
//   tailor @ 2166784  : 262,144
//   Wqk    @ 2428928  : 131,072
//   matT   @ 2560000  : 1,048,576
//   QnT    @ 3608576  : 8,388,608
//   Kn     @ 11997184 : 8,388,608                 (end 20,385,792)
// ---------------------------------------------------------------------------
extern "C" void kernel_launch(void* const* d_in, const int* in_sizes, int n_in,
                              void* d_out, int out_size, void* d_ws, size_t ws_size,
                              hipStream_t stream) {
  const float* x     = (const float*)d_in[0];
  const float* Wq    = (const float*)d_in[1];
  const float* bq    = (const float*)d_in[2];
  const float* Wk    = (const float*)d_in[3];
  const float* bk    = (const float*)d_in[4];
  const float* Wv    = (const float*)d_in[5];
  const float* bv    = (const float*)d_in[6];
  const float* gamma = (const float*)d_in[7];
  float* out = (float*)d_out;
  char* ws = (char*)d_ws;

  float* T      = (float*)(ws + 0);
  float* xsum   = (float*)(ws + 2097152);
  float* Ksum   = (float*)(ws + 2129920);
  float* Vsum   = (float*)(ws + 2134016);
  float* tailor = (float*)(ws + 2166784);
  unsigned short* Wqk  = (unsigned short*)(ws + 2428928);
  unsigned short* matT = (unsigned short*)(ws + 2560000);
  unsigned short* QnT  = (unsigned short*)(ws + 3608576);
  unsigned short* Kn   = (unsigned short*)(ws + 11997184);

  k_prep<<<256, 256, 0, stream>>>(Wq, Wk, Wqk, xsum, Ksum, T);
  k_qk<<<dim3(32, 16), 256, 0, stream>>>(x, Wqk, bq, bk, QnT, Kn, Ksum);
  k_t<<<dim3(8, 4, 16), 256, 0, stream>>>(x, Kn, T, xsum, QnT, Ksum, tailor);
  k_mat<<<dim3(16, 16), 256, 0, stream>>>(T, Wv, bv, xsum, Ksum, matT, Vsum);
  k_out<<<dim3(32, 16), 256, 0, stream>>>(QnT, matT, tailor, Vsum, gamma, out);
}

// Round 8
// 320.570 us; speedup vs baseline: 1.0098x; 1.0098x over previous
//
#include <hip/hip_runtime.h>

// ---------------------------------------------------------------------------
// Attention_33638183862624  (linear "Taylor-softmax" attention)
// B=16, C=512, CQK=64, N=4096.  fp32 in/out, bf16 MFMA internally.
// FINAL (R9 = R7 revert, best measured 321.2us):
//   fixed harness floor ~220us; kernels ~100us, each within 1-5us of its
//   traffic floor: k_qk 27 (floor 24), k_t 26, k_red 3, k_mat ~9,
//   k_out 22 = write roofline (81% HBM peak, 144MB mandatory traffic).
// R8 (direct atomics, no k_red) = 323.7us -> reverted; atomic drain vs
//   store->reduce->read differs by ~+-2-3us = noise floor.
// gfx950 note: LDS dbuf pointer ARRAYS indexed by runtime values fail to
//   compile ("static initializer addrspacecast"); use smem + pb*OFFSET.
// ---------------------------------------------------------------------------

typedef __attribute__((ext_vector_type(8))) short short8_t;
typedef __attribute__((ext_vector_type(4))) float f32x4;

__device__ __forceinline__ unsigned short f2bf(float f) {
  union { float f; unsigned u; } v; v.f = f;
  unsigned r = v.u + 0x7FFFu + ((v.u >> 16) & 1u);   // RNE
  return (unsigned short)(r >> 16);
}
__device__ __forceinline__ float bf2f(unsigned short h) {
  union { unsigned u; float f; } v; v.u = ((unsigned)h) << 16;
  return v.f;
}

#define MFMA(a, b, c) __builtin_amdgcn_mfma_f32_16x16x32_bf16((a), (b), (c), 0, 0, 0)

// ---------------------------------------------------------------------------
// k_prep: pack Wq/Wk into bf16 [128][512]; zero xsum/Ksum.
// ---------------------------------------------------------------------------
__global__ void k_prep(const float* __restrict__ Wq, const float* __restrict__ Wk,
                       unsigned short* __restrict__ Wqk,
                       float* __restrict__ xsum, float* __restrict__ Ksum) {
  int idx = blockIdx.x * 256 + threadIdx.x;       // 65536 total
  int o = idx >> 9, c = idx & 511;
  float v = (o < 64) ? Wq[o * 512 + c] : Wk[(o - 64) * 512 + c];
  Wqk[idx] = f2bf(v);
  if (idx < 8192) xsum[idx] = 0.f;
  if (idx < 1024) Ksum[idx] = 0.f;
}

// ---------------------------------------------------------------------------
// k_qk: per batch GEMM QK[128 o][4096 n] = Wqk[128][512] * x[512][4096]
// (27us vs 24us traffic floor -- done.)
// ---------------------------------------------------------------------------
__launch_bounds__(256, 2)
__global__ void k_qk(const float* __restrict__ x, const unsigned short* __restrict__ Wqk,
                     const float* __restrict__ bq, const float* __restrict__ bk,
                     unsigned short* __restrict__ QnT, unsigned short* __restrict__ KnG,
                     float* __restrict__ Ksum) {
  __shared__ __align__(16) unsigned char smem[77312];
  unsigned short* SAb[2] = {(unsigned short*)(smem + 0),
                            (unsigned short*)(smem + 18432)};   // 128 x 72 each
  unsigned short* SBb[2] = {(unsigned short*)(smem + 36864),
                            (unsigned short*)(smem + 55296)};   // 128 x 72 each
  unsigned short* EQ = (unsigned short*)(smem + 0);       // 128 x 72 (epilogue)
  unsigned short* EK = (unsigned short*)(smem + 18432);   // 64 x 136 (epilogue)
  float* ssq   = (float*)(smem + 73728);                  // [4][128]
  float* invq  = (float*)(smem + 75776);                  // [128]
  float* invk  = (float*)(smem + 76288);                  // [128]
  float* biasL = (float*)(smem + 76800);                  // [128]

  const int t = threadIdx.x;
  const int lane = t & 63, w = t >> 6;
  const int l15 = lane & 15, quad = lane >> 4;
  const int nt = blockIdx.x, b = blockIdx.y;
  const int n0 = nt * 128;
  const float* xb = x + (size_t)b * 512 * 4096;

  if (t < 128) biasL[t] = (t < 64) ? bq[t] : bk[t - 64];

  f32x4 acc[2][8];
#pragma unroll
  for (int i = 0; i < 2; ++i)
#pragma unroll
    for (int j = 0; j < 8; ++j) acc[i][j] = (f32x4){0.f, 0.f, 0.f, 0.f};

  const int nB = t & 127;
  const int cgB = t >> 7;
  const float* bsrc0 = xb + (size_t)(cgB * 32) * 4096 + n0 + nB;

  short8_t apre[4];
  float bpre[32];

#define QK_LOADA(kc_) do {                                                     \
    const int c0_ = (kc_) * 64;                                                \
    _Pragma("unroll")                                                          \
    for (int p = 0; p < 4; ++p) {                                              \
      int gid = t + p * 256; int o_ = gid >> 3, cg = gid & 7;                  \
      apre[p] = *(const short8_t*)(Wqk + o_ * 512 + c0_ + cg * 8);             \
    } } while (0)

#define QK_LOADB(kc_) do {                                                     \
    const float* s_ = bsrc0 + (size_t)(kc_) * 64 * 4096;                       \
    _Pragma("unroll")                                                          \
    for (int i = 0; i < 32; ++i) bpre[i] = s_[(size_t)i * 4096];               \
    } while (0)

#define QK_STORE(pb) do {                                                      \
    unsigned short* SAp = SAb[pb]; unsigned short* SBp = SBb[pb];              \
    _Pragma("unroll")                                                          \
    for (int p = 0; p < 4; ++p) {                                              \
      int gid = t + p * 256; int o_ = gid >> 3, cg = gid & 7;                  \
      *(short8_t*)(SAp + o_ * 72 + cg * 8) = apre[p];                          \
    }                                                                          \
    _Pragma("unroll")                                                          \
    for (int j = 0; j < 4; ++j) {                                              \
      short8_t v_;                                                             \
      _Pragma("unroll")                                                        \
      for (int e = 0; e < 8; ++e) v_[e] = (short)f2bf(bpre[j * 8 + e]);        \
      *(short8_t*)(SBp + nB * 72 + cgB * 32 + j * 8) = v_;                     \
    } } while (0)

#define QK_MM(pb) do {                                                         \
    const unsigned short* SAp = SAb[pb]; const unsigned short* SBp = SBb[pb];  \
    _Pragma("unroll")                                                          \
    for (int s = 0; s < 2; ++s) {                                              \
      short8_t a0 = *(const short8_t*)(SAp + (w * 32 + l15) * 72 + s * 32 + quad * 8);      \
      short8_t a1 = *(const short8_t*)(SAp + (w * 32 + 16 + l15) * 72 + s * 32 + quad * 8); \
      _Pragma("unroll")                                                        \
      for (int tc = 0; tc < 8; ++tc) {                                         \
        short8_t bf_ = *(const short8_t*)(SBp + (tc * 16 + l15) * 72 + s * 32 + quad * 8);  \
        acc[0][tc] = MFMA(a0, bf_, acc[0][tc]);                                \
        acc[1][tc] = MFMA(a1, bf_, acc[1][tc]);                                \
      } } } while (0)

  QK_LOADA(0); QK_LOADB(0);
#pragma unroll
  for (int kc = 0; kc < 8; ++kc) {
    const int pb = kc & 1;
    QK_STORE(pb);
    if (kc < 7) { QK_LOADA(kc + 1); QK_LOADB(kc + 1); }
    __syncthreads();
    QK_MM(pb);
  }
  __syncthreads();

#pragma unroll
  for (int trl = 0; trl < 2; ++trl)
#pragma unroll
    for (int reg = 0; reg < 4; ++reg) {
      int o = w * 32 + trl * 16 + quad * 4 + reg;
      float bias = biasL[o];
#pragma unroll
      for (int tc = 0; tc < 8; ++tc) acc[trl][tc][reg] += bias;
    }

#pragma unroll
  for (int tc = 0; tc < 8; ++tc) {
    float v = 0.f;
#pragma unroll
    for (int trl = 0; trl < 2; ++trl)
#pragma unroll
      for (int reg = 0; reg < 4; ++reg) {
        float q = acc[trl][tc][reg];
        v += q * q;
      }
    v += __shfl_xor(v, 16);
    v += __shfl_xor(v, 32);
    if (quad == 0) ssq[w * 128 + tc * 16 + l15] = v;
  }
  __syncthreads();
  if (t < 128) {
    float qs = ssq[t] + ssq[128 + t];
    float ks = ssq[256 + t] + ssq[384 + t];
    invq[t] = 1.0f / fmaxf(sqrtf(qs), 1e-6f);
    invk[t] = 1.0f / fmaxf(sqrtf(ks), 1e-6f);
  }
  __syncthreads();

  if (w < 2) {
#pragma unroll
    for (int trl = 0; trl < 2; ++trl)
#pragma unroll
      for (int tc = 0; tc < 8; ++tc) {
        int n = tc * 16 + l15;
        float inv = invq[n];
#pragma unroll
        for (int reg = 0; reg < 4; ++reg) {
          int o = w * 32 + trl * 16 + quad * 4 + reg;
          EQ[n * 72 + o] = f2bf(acc[trl][tc][reg] * inv);
        }
      }
  } else {
#pragma unroll
    for (int trl = 0; trl < 2; ++trl)
#pragma unroll
      for (int reg = 0; reg < 4; ++reg) {
        int m = (w - 2) * 32 + trl * 16 + quad * 4 + reg;
        float p = 0.f;
#pragma unroll
        for (int tc = 0; tc < 8; ++tc) {
          int n = tc * 16 + l15;
          float val = acc[trl][tc][reg] * invk[n];
          EK[m * 136 + n] = f2bf(val);
          p += val;
        }
        p += __shfl_xor(p, 1);
        p += __shfl_xor(p, 2);
        p += __shfl_xor(p, 4);
        p += __shfl_xor(p, 8);
        if (l15 == 0) atomicAdd(Ksum + b * 64 + m, p);
      }
  }
  __syncthreads();

  unsigned short* qdst = QnT + ((size_t)b * 4096 + n0) * 64;
#pragma unroll
  for (int p = 0; p < 4; ++p) {
    int idx = t + p * 256;
    int row = idx >> 3, seg = idx & 7;
    *(short8_t*)(qdst + row * 64 + seg * 8) = *(const short8_t*)(EQ + row * 72 + seg * 8);
  }
  unsigned short* kdst = KnG + (size_t)b * 64 * 4096 + n0;
#pragma unroll
  for (int p = 0; p < 4; ++p) {
    int idx = t + p * 256;
    int row = idx >> 4, seg = idx & 15;
    *(short8_t*)(kdst + (size_t)row * 4096 + seg * 8) =
        *(const short8_t*)(EK + row * 136 + seg * 8);
  }
#undef QK_LOADA
#undef QK_LOADB
#undef QK_STORE
#undef QK_MM
}

// ---------------------------------------------------------------------------
// k_t:  Tpart[ns][b][64 m][512 k] = sum_{n in split ns} Kn[m,n]*x[k,n]
// + xsum atomics + tailor[b][n] (Ksum final here).  BK=64 dbuf+prefetch.
// grid (8 nsplits, 4 ctiles, 16 batches), 256 threads.
// ---------------------------------------------------------------------------
__launch_bounds__(256, 2)
__global__ void k_t(const float* __restrict__ x, const unsigned short* __restrict__ KnG,
                    float* __restrict__ Tpart, float* __restrict__ xsum,
                    const unsigned short* __restrict__ QnT,
                    const float* __restrict__ Ksum, float* __restrict__ tailor) {
  __shared__ __align__(16) unsigned char smem[55552];
  unsigned short* SAb[2] = {(unsigned short*)(smem + 0),
                            (unsigned short*)(smem + 9216)};    // 64 x 72 each
  unsigned short* SBb[2] = {(unsigned short*)(smem + 18432),
                            (unsigned short*)(smem + 36864)};   // 128 x 72 each
  float* Ksl = (float*)(smem + 55296);                          // [64]
  const int t = threadIdx.x;
  const int lane = t & 63, w = t >> 6;
  const int l15 = lane & 15, quad = lane >> 4;
  const int ns = blockIdx.x, ct = blockIdx.y, b = blockIdx.z;
  const int c0 = ct * 128;
  const float* xb = x + (size_t)b * 512 * 4096;
  const unsigned short* Knb = KnG + (size_t)b * 64 * 4096 + ns * 512;

  if (t < 64) Ksl[t] = Ksum[b * 64 + t];

  f32x4 acc[4][2];
#pragma unroll
  for (int i = 0; i < 4; ++i)
#pragma unroll
    for (int j = 0; j < 2; ++j) acc[i][j] = (f32x4){0.f, 0.f, 0.f, 0.f};

  const int row = t >> 1, half = t & 1;
  float xs = 0.f;
  const float* bbase = xb + (size_t)(c0 + row) * 4096 + ns * 512 + half * 32;

  short8_t apre[2];
  f32x4 bpre[8];

#define T_LOADA(ch_) do {                                                      \
    _Pragma("unroll")                                                          \
    for (int p = 0; p < 2; ++p) {                                              \
      int gid = t + p * 256; int m_ = gid >> 3, cg = gid & 7;                  \
      apre[p] = *(const short8_t*)(Knb + (size_t)m_ * 4096 + (ch_) * 64 + cg * 8); \
    } } while (0)

#define T_LOADB(ch_) do {                                                      \
    const float* s_ = bbase + (ch_) * 64;                                      \
    _Pragma("unroll")                                                          \
    for (int q = 0; q < 8; ++q) bpre[q] = *(const f32x4*)(s_ + q * 4);         \
    } while (0)

#define T_STORE(pb) do {                                                       \
    unsigned short* SAp = SAb[pb]; unsigned short* SBp = SBb[pb];              \
    _Pragma("unroll")                                                          \
    for (int p = 0; p < 2; ++p) {                                              \
      int gid = t + p * 256; int m_ = gid >> 3, cg = gid & 7;                  \
      *(short8_t*)(SAp + m_ * 72 + cg * 8) = apre[p];                          \
    }                                                                          \
    _Pragma("unroll")                                                          \
    for (int j = 0; j < 4; ++j) {                                              \
      short8_t v_;                                                             \
      _Pragma("unroll")                                                        \
      for (int e = 0; e < 4; ++e) {                                            \
        float f0 = bpre[j * 2][e], f1 = bpre[j * 2 + 1][e];                    \
        xs += f0 + f1;                                                         \
        v_[e] = (short)f2bf(f0); v_[4 + e] = (short)f2bf(f1);                  \
      }                                                                        \
      *(short8_t*)(SBp + row * 72 + half * 32 + j * 8) = v_;                   \
    } } while (0)

#define T_MM(pb) do {                                                          \
    const unsigned short* SAp = SAb[pb]; const unsigned short* SBp = SBb[pb];  \
    _Pragma("unroll")                                                          \
    for (int s = 0; s < 2; ++s) {                                              \
      short8_t af[4];                                                          \
      _Pragma("unroll")                                                        \
      for (int tm = 0; tm < 4; ++tm)                                           \
        af[tm] = *(const short8_t*)(SAp + (tm * 16 + l15) * 72 + s * 32 + quad * 8); \
      _Pragma("unroll")                                                        \
      for (int tcl = 0; tcl < 2; ++tcl) {                                      \
        short8_t bf_ = *(const short8_t*)(SBp + (w * 32 + tcl * 16 + l15) * 72 + s * 32 + quad * 8); \
        _Pragma("unroll")                                                      \
        for (int tm = 0; tm < 4; ++tm) acc[tm][tcl] = MFMA(af[tm], bf_, acc[tm][tcl]); \
      } } } while (0)

  T_LOADA(0); T_LOADB(0);
#pragma unroll
  for (int ch = 0; ch < 8; ++ch) {
    const int pb = ch & 1;
    T_STORE(pb);
    if (ch < 7) { T_LOADA(ch + 1); T_LOADB(ch + 1); }
    __syncthreads();
    if (ch == 0 && t < 128) {
      int n = ns * 512 + ct * 128 + t;
      const unsigned short* q = QnT + ((size_t)b * 4096 + n) * 64;
      float d = 0.f;
#pragma unroll
      for (int s8 = 0; s8 < 8; ++s8) {
        short8_t qv = *(const short8_t*)(q + s8 * 8);
#pragma unroll
        for (int e = 0; e < 8; ++e)
          d += bf2f((unsigned short)qv[e]) * Ksl[s8 * 8 + e];
      }
      tailor[b * 4096 + n] = 1.0f / fmaxf(4096.0f + d, 1e-6f);
    }
    T_MM(pb);
  }

  xs += __shfl_xor(xs, 1);
  if (half == 0) atomicAdd(xsum + b * 512 + c0 + row, xs);
  float* Tp = Tpart + ((size_t)(ns * 16 + b) * 64) * 512;
#pragma unroll
  for (int tm = 0; tm < 4; ++tm)
#pragma unroll
    for (int tcl = 0; tcl < 2; ++tcl)
#pragma unroll
      for (int reg = 0; reg < 4; ++reg) {
        int m = tm * 16 + quad * 4 + reg;
        int c = c0 + w * 32 + tcl * 16 + l15;
        Tp[(size_t)m * 512 + c] = acc[tm][tcl][reg];
      }
#undef T_LOADA
#undef T_LOADB
#undef T_STORE
#undef T_MM
}

// ---------------------------------------------------------------------------
// k_red: T[b][m][k] = sum_{ns<8} Tpart[ns][b][m][k]   (16.8MB -> 2MB, ~3us)
// k_mat's 16x c-block re-read then hits the 2MB T (L2-hot) instead of the
// 16.8MB Tpart (268MB of L3 traffic -- the R4 regression).
// ---------------------------------------------------------------------------
__global__ void k_red(const float* __restrict__ Tpart, float* __restrict__ T) {
  size_t idx = (size_t)blockIdx.x * 256 + threadIdx.x;   // 131072 f32x4 total
  const f32x4* p = (const f32x4*)Tpart + idx;
  f32x4 s = p[0];
#pragma unroll
  for (int ns = 1; ns < 8; ++ns) s += p[(size_t)ns * 131072];
  ((f32x4*)T)[idx] = s;
}

// ---------------------------------------------------------------------------
// k_mat: matrix[m][c] = sum_k T[m][k]*Wv[c][k] + bv[c]*Ksum[m] -> matT[c][m]
//        Vsum[c] = Wv[c,:]*xsum + 4096*bv[c]
// 2m x 4c register blocking, f32x4 LDS reads.  Reads reduced T (2MB).
// grid (16 cblocks, 16 batches), 256 threads; c-range 32 per block.
// ---------------------------------------------------------------------------
__launch_bounds__(256, 2)
__global__ void k_mat(const float* __restrict__ T, const float* __restrict__ Wv,
                      const float* __restrict__ bv, const float* __restrict__ xsum,
                      const float* __restrict__ Ksum,
                      unsigned short* __restrict__ matT, float* __restrict__ Vsum) {
  __shared__ __align__(16) unsigned char smem[27136];
  float* ST = (float*)smem;             // 64 x 68
  float* SW = (float*)(smem + 17408);   // 32 x 68
  float* SV = (float*)(smem + 26112);   // 256
  const int t = threadIdx.x;
  const int cb = blockIdx.x, b = blockIdx.y;
  const int c0 = cb * 32;
  const int mp = t >> 3, cs = t & 7;    // rows {2mp,2mp+1}, cols {cs+8j}
  f32x4 acc0 = (f32x4){0.f, 0.f, 0.f, 0.f};
  f32x4 acc1 = (f32x4){0.f, 0.f, 0.f, 0.f};

  for (int kc = 0; kc < 8; ++kc) {
    __syncthreads();
#pragma unroll
    for (int p = 0; p < 4; ++p) {
      int idx = t + p * 256;
      int row = idx >> 4, f4 = idx & 15;
      *(f32x4*)(ST + row * 68 + f4 * 4) =
          *(const f32x4*)(T + ((size_t)b * 64 + row) * 512 + kc * 64 + f4 * 4);
    }
#pragma unroll
    for (int p = 0; p < 2; ++p) {
      int idx = t + p * 256;
      int row = idx >> 4, f4 = idx & 15;
      *(f32x4*)(SW + row * 68 + f4 * 4) =
          *(const f32x4*)(Wv + (size_t)(c0 + row) * 512 + kc * 64 + f4 * 4);
    }
    __syncthreads();
#pragma unroll 4
    for (int kk = 0; kk < 64; kk += 4) {
      f32x4 t0 = *(const f32x4*)(ST + (2 * mp) * 68 + kk);
      f32x4 t1 = *(const f32x4*)(ST + (2 * mp + 1) * 68 + kk);
#pragma unroll
      for (int j = 0; j < 4; ++j) {
        f32x4 wv = *(const f32x4*)(SW + (cs + j * 8) * 68 + kk);
#pragma unroll
        for (int e = 0; e < 4; ++e) {
          acc0[j] = fmaf(t0[e], wv[e], acc0[j]);
          acc1[j] = fmaf(t1[e], wv[e], acc1[j]);
        }
      }
    }
  }
  float ks0 = Ksum[b * 64 + 2 * mp];
  float ks1 = Ksum[b * 64 + 2 * mp + 1];
#pragma unroll
  for (int j = 0; j < 4; ++j) {
    int c = c0 + cs + j * 8;
    float bvc = bv[c];
    unsigned lo = f2bf(acc0[j] + bvc * ks0);
    unsigned hi = f2bf(acc1[j] + bvc * ks1);
    *(unsigned*)(matT + ((size_t)b * 512 + c) * 64 + 2 * mp) = lo | (hi << 16);
  }
  {
    int cc = t >> 3, kp = t & 7;
    const float* wr = Wv + (size_t)(c0 + cc) * 512 + kp * 64;
    const float* xr = xsum + b * 512 + kp * 64;
    float s = 0.f;
    for (int i = 0; i < 64; ++i) s += wr[i] * xr[i];
    SV[cc * 8 + kp] = s;
  }
  __syncthreads();
  if (t < 32) {
    float s = 0.f;
#pragma unroll
    for (int i = 0; i < 8; ++i) s += SV[t * 8 + i];
    int c = c0 + t;
    Vsum[b * 512 + c] = s + 4096.0f * bv[c];
  }
}

// ---------------------------------------------------------------------------
// k_out: ct-merged.  grid (32 nt, 16 b), 256 threads.  Stage QnT/tail/Vsum
// once; loop ct=0..3 with reg-prefetch + LDS dbuf (byte-offset arithmetic)
// for matT; MFMA + store per ct.  22us = write roofline (81% HBM peak).
// ---------------------------------------------------------------------------
__launch_bounds__(256, 2)
__global__ void k_out(const unsigned short* __restrict__ QnT,
                      const unsigned short* __restrict__ matT,
                      const float* __restrict__ tailG, const float* __restrict__ Vsum,
                      const float* __restrict__ gamma, float* __restrict__ out) {
  __shared__ __align__(16) unsigned char smem[57856];
  unsigned short* SB = (unsigned short*)(smem + 36864);   // 128 x 72 (QnT)
  float* tail = (float*)(smem + 55296);                   // 128
  float* vs   = (float*)(smem + 55808);                   // 512
  const int t = threadIdx.x;
  const int lane = t & 63, w = t >> 6;
  const int l15 = lane & 15, quad = lane >> 4;
  const int nt = blockIdx.x, b = blockIdx.y;
  const int n0 = nt * 128;

  const unsigned short* bsrc = QnT + ((size_t)b * 4096 + n0) * 64;
#pragma unroll
  for (int p = 0; p < 4; ++p) {
    int idx = t + p * 256;
    int row = idx >> 3, seg = idx & 7;
    *(short8_t*)(SB + row * 72 + seg * 8) = *(const short8_t*)(bsrc + row * 64 + seg * 8);
  }
  if (t < 128) tail[t] = tailG[b * 4096 + n0 + t];
  vs[t] = Vsum[b * 512 + t];
  vs[256 + t] = Vsum[b * 512 + 256 + t];
  const float g = gamma[0];
  float* ob = out + (size_t)b * 512 * 4096;
  const unsigned short* asrc = matT + (size_t)b * 512 * 64;

  short8_t areg[4];
#pragma unroll
  for (int p = 0; p < 4; ++p) {
    int idx = t + p * 256;
    int row = idx >> 3, seg = idx & 7;
    areg[p] = *(const short8_t*)(asrc + row * 64 + seg * 8);
  }
  for (int ct = 0; ct < 4; ++ct) {
    unsigned short* SAp = (unsigned short*)(smem + (ct & 1) * 18432);
#pragma unroll
    for (int p = 0; p < 4; ++p) {
      int idx = t + p * 256;
      int row = idx >> 3, seg = idx & 7;
      *(short8_t*)(SAp + row * 72 + seg * 8) = areg[p];
    }
    if (ct < 3) {
      const unsigned short* an = asrc + (size_t)(ct + 1) * 128 * 64;
#pragma unroll
      for (int p = 0; p < 4; ++p) {
        int idx = t + p * 256;
        int row = idx >> 3, seg = idx & 7;
        areg[p] = *(const short8_t*)(an + row * 64 + seg * 8);
      }
    }
    __syncthreads();
    f32x4 acc[2][8];
#pragma unroll
    for (int i = 0; i < 2; ++i)
#pragma unroll
      for (int j = 0; j < 8; ++j) acc[i][j] = (f32x4){0.f, 0.f, 0.f, 0.f};
#pragma unroll
    for (int s = 0; s < 2; ++s) {
      short8_t a0 = *(const short8_t*)(SAp + (w * 32 + l15) * 72 + s * 32 + quad * 8);
      short8_t a1 = *(const short8_t*)(SAp + (w * 32 + 16 + l15) * 72 + s * 32 + quad * 8);
#pragma unroll
      for (int tc = 0; tc < 8; ++tc) {
        short8_t bfr = *(const short8_t*)(SB + (tc * 16 + l15) * 72 + s * 32 + quad * 8);
        acc[0][tc] = MFMA(a0, bfr, acc[0][tc]);
        acc[1][tc] = MFMA(a1, bfr, acc[1][tc]);
      }
    }
    const int c0 = ct * 128;
#pragma unroll
    for (int trl = 0; trl < 2; ++trl)
#pragma unroll
      for (int tc = 0; tc < 8; ++tc) {
        int n = tc * 16 + l15;
        float tl = tail[n] * g;
#pragma unroll
        for (int reg = 0; reg < 4; ++reg) {
          int cl = w * 32 + trl * 16 + quad * 4 + reg;
          float val = tl * (vs[c0 + cl] + acc[trl][tc][reg]);
          ob[(size_t)(c0 + cl) * 4096 + n0 + n] = val;
        }
      }
    __syncthreads();
  }
}

// ---------------------------------------------------------------------------
// workspace layout (bytes):
//   Tpart  @ 0         : 8*16*64*512*4 = 16,777,216  (fully overwritten)
//   T      @ 16777216  : 16*64*512*4   = 2,097,152   (k_red output)
//   xsum   @ 18874368  : 32,768      (zeroed by k_prep)
//   Ksum   @ 18907136  : 4,096       (zeroed by k_prep)
//   Vsum   @ 18911232  : 32,768
//   tailor @ 18944000  : 262,144
//   Wqk    @ 19206144  : 131,072
//   matT   @ 19337216  : 1,048,576
//   QnT    @ 20385792  : 8,388,608
//   Kn     @ 28774400  : 8,388,608                  (end 37,163,008)
// ---------------------------------------------------------------------------
extern "C" void kernel_launch(void* const* d_in, const int* in_sizes, int n_in,
                              void* d_out, int out_size, void* d_ws, size_t ws_size,
                              hipStream_t stream) {
  const float* x     = (const float*)d_in[0];
  const float* Wq    = (const float*)d_in[1];
  const float* bq    = (const float*)d_in[2];
  const float* Wk    = (const float*)d_in[3];
  const float* bk    = (const float*)d_in[4];
  const float* Wv    = (const float*)d_in[5];
  const float* bv    = (const float*)d_in[6];
  const float* gamma = (const float*)d_in[7];
  float* out = (float*)d_out;
  char* ws = (char*)d_ws;

  float* Tpart  = (float*)(ws + 0);
  float* T      = (float*)(ws + 16777216);
  float* xsum   = (float*)(ws + 18874368);
  float* Ksum   = (float*)(ws + 18907136);
  float* Vsum   = (float*)(ws + 18911232);
  float* tailor = (float*)(ws + 18944000);
  unsigned short* Wqk  = (unsigned short*)(ws + 19206144);
  unsigned short* matT = (unsigned short*)(ws + 19337216);
  unsigned short* QnT  = (unsigned short*)(ws + 20385792);
  unsigned short* Kn   = (unsigned short*)(ws + 28774400);

  k_prep<<<256, 256, 0, stream>>>(Wq, Wk, Wqk, xsum, Ksum);
  k_qk<<<dim3(32, 16), 256, 0, stream>>>(x, Wqk, bq, bk, QnT, Kn, Ksum);
  k_t<<<dim3(8, 4, 16), 256, 0, stream>>>(x, Kn, Tpart, xsum, QnT, Ksum, tailor);
  k_red<<<512, 256, 0, stream>>>(Tpart, T);
  k_mat<<<dim3(16, 16), 256, 0, stream>>>(T, Wv, bv, xsum, Ksum, matT, Vsum);
  k_out<<<dim3(32, 16), 256, 0, stream>>>(QnT, matT, tailor, Vsum, gamma, out);
}